// Round 15
// baseline (124.020 us; speedup 1.0000x reference)
//
#include <hip/hip_runtime.h>
#include <math.h>

// Problem: x[B=32][N=2048][K=8], W[N][C=32][J=16][K=8], R[N][C]
// out[b][c][j] = squash_j( sum_n softmax_n(R)[n,c] * sum_k W[n,c,j,k]*x[b,n,k] )
// Single fused kernel: main accumulates with UNNORMALIZED w = exp(R[n][c]) into
// per-block partials P; the LAST-arriving block per cq (device-scope atomic
// counter) computes denominators, reduces P, squashes, writes out. Deterministic:
// exactly one block reduces, with a fixed summation order. cnt zeroed per launch
// by a 32-byte hipMemsetAsync (graph-capturable).

#define NN 2048
#define CC 32

__device__ __forceinline__ void g2l16(const float* g, float* l) {
  __builtin_amdgcn_global_load_lds((const __attribute__((address_space(1))) void*)g,
                                   (__attribute__((address_space(3))) void*)l, 16, 0, 0);
}

// ---------- fused kernel: R13-verbatim main + last-block reduce ----------
// grid 512: chunk = bid&63 (32 n), cq = bid>>6 (4 c). XCD = bid%8 = chunk%8 -> the 8
// cq-blocks of a chunk share an XCD. block 512 = 8 waves; LDS 80KB -> 2 blocks/CU.
// Wave ws owns n = n0+ws*4..+4; W 3-buf ring (2-ahead), x wave-private in LDS.
// Counted vmcnt before EVERY compute; order pinned by sched_barrier(0) (R9 lesson);
// lgkmcnt(0) WAR guard before ring-wrap. NO occupancy attributes (R4/R6 spill).
__global__ void __launch_bounds__(512) caps_fused(const float* __restrict__ x,
                                                  const float* __restrict__ W,
                                                  const float* __restrict__ R,
                                                  float* __restrict__ P,
                                                  int* __restrict__ cnt,
                                                  float* __restrict__ out) {
  const int bid = blockIdx.x;
  const int cq = bid >> 6;
  const int chunk = bid & 63;
  const int n0 = chunk * 32;
  const int tid = threadIdx.x;
  const int ws = tid >> 6;
  const int lane = tid & 63;
  const int j = lane & 15;
  const int bo = lane >> 4;

  extern __shared__ float smem[];   // 8 x 2560 floats = 80 KB
  float* wREG = smem + ws * 2560;
  float* wW = wREG;                 // ring: 3 bufs x 512
  float* wX = wREG + 1536;          // 4 n x 256
  const int nw = n0 + ws * 4;

  // ---- R loads first (pinned oldest) ----
  float4 rq[4];
#pragma unroll
  for (int nl = 0; nl < 4; ++nl)
    rq[nl] = *(const float4*)(R + (size_t)(nw + nl) * CC + cq * 4);
  __builtin_amdgcn_sched_barrier(0);

  auto stageW = [&](int nl, int buf) {
#pragma unroll
    for (int i = 0; i < 2; ++i) {
      int S = i * 64 + lane;
      int g = S ^ (((S >> 2) ^ (S >> 4)) & 1) ^ (((S >> 3) & 1) << 1) ^ (((S >> 4) & 1) << 2);
      g2l16(W + (size_t)(nw + nl) * 4096 + cq * 512 + g * 4, wW + buf * 512 + i * 256);
    }
  };

  // ---- prologue: W0, x, W1, W2 (pinned order; 10 g2l16 outstanding) ----
  stageW(0, 0);
  __builtin_amdgcn_sched_barrier(0);
  {
    int g2 = lane ^ ((lane >> 4) << 1);   // slot 'lane' holds granule g2
    int b = g2 >> 1, kq = g2 & 1;
    const float* xs = x + (size_t)b * (NN * 8) + kq * 4;
#pragma unroll
    for (int nl = 0; nl < 4; ++nl)
      g2l16(xs + (size_t)(nw + nl) * 8, wX + nl * 256);
  }
  __builtin_amdgcn_sched_barrier(0);
  stageW(1, 1);
  __builtin_amdgcn_sched_barrier(0);
  stageW(2, 2);
  __builtin_amdgcn_sched_barrier(0);

  // unnormalized routing weights
  float rv[4][4];
#pragma unroll
  for (int nl = 0; nl < 4; ++nl) {
    rv[nl][0] = expf(rq[nl].x);
    rv[nl][1] = expf(rq[nl].y);
    rv[nl][2] = expf(rq[nl].z);
    rv[nl][3] = expf(rq[nl].w);
  }

  float acc[4][8];
#pragma unroll
  for (int a = 0; a < 4; ++a)
#pragma unroll
    for (int b = 0; b < 8; ++b) acc[a][b] = 0.f;

  const int jsw = j >> 1;

  auto compute = [&](int nl, int buf) {
    const float* Wn = wW + buf * 512;
    const float* Xn = wX + nl * 256;
#pragma unroll
    for (int kh = 0; kh < 2; ++kh) {
      float4 xv[8];
#pragma unroll
      for (int bi = 0; bi < 8; ++bi) {
        int G = (bo * 8 + bi) * 2 + kh;
        int S = G ^ ((G >> 4) << 1);
        xv[bi] = *(const float4*)(Xn + S * 4);
      }
#pragma unroll
      for (int ci = 0; ci < 4; ++ci) {
        int slot = (ci * 32 + j * 2 + kh) ^ jsw;
        float4 wf = *(const float4*)(Wn + slot * 4);
        float rvv = rv[nl][ci];
        float w0 = wf.x * rvv, w1 = wf.y * rvv, w2 = wf.z * rvv, w3 = wf.w * rvv;
#pragma unroll
        for (int bi = 0; bi < 8; ++bi) {
          float a = acc[ci][bi];
          a = fmaf(w0, xv[bi].x, a);
          a = fmaf(w1, xv[bi].y, a);
          a = fmaf(w2, xv[bi].z, a);
          a = fmaf(w3, xv[bi].w, a);
          acc[ci][bi] = a;
        }
      }
    }
  };

  // ---- pipeline: 2-ahead ring; counted waits only; 0 barriers ----
  asm volatile("s_waitcnt vmcnt(4)" ::: "memory");   // W0 + x landed (W1,W2 in flight)
  __builtin_amdgcn_sched_barrier(0);
  compute(0, 0);
  asm volatile("s_waitcnt lgkmcnt(0)" ::: "memory"); // compute0 LDS reads retired
  __builtin_amdgcn_sched_barrier(0);
  stageW(3, 0);                                      // ring wrap onto buf0
  __builtin_amdgcn_sched_barrier(0);
  asm volatile("s_waitcnt vmcnt(4)" ::: "memory");   // W1 landed (W2,W3 in flight)
  __builtin_amdgcn_sched_barrier(0);
  compute(1, 1);
  asm volatile("s_waitcnt vmcnt(2)" ::: "memory");   // W2 landed (W3 in flight)
  __builtin_amdgcn_sched_barrier(0);
  compute(2, 2);
  asm volatile("s_waitcnt vmcnt(0)" ::: "memory");   // W3 landed
  __builtin_amdgcn_sched_barrier(0);
  compute(3, 0);

  // ---- epilogue: dump into own region, 1 barrier, block-sum, P write ----
#pragma unroll
  for (int ci = 0; ci < 4; ++ci)
#pragma unroll
    for (int bi = 0; bi < 8; ++bi)
      wREG[(ci * 8 + bi) * 64 + lane] = acc[ci][bi];
  __syncthreads();
  {
    const int t4 = tid * 4;
    float4 ssum = make_float4(0.f, 0.f, 0.f, 0.f);
#pragma unroll
    for (int w = 0; w < 8; ++w) {
      float4 v = *(const float4*)(smem + (size_t)w * 2560 + t4);
      ssum.x += v.x; ssum.y += v.y; ssum.z += v.z; ssum.w += v.w;
    }
    *(float4*)(P + (size_t)bid * 2048 + t4) = ssum;
  }

  // ---- completion protocol: release P, count arrivals; last block reduces ----
  __threadfence();              // each thread: its P writes device-visible
  __syncthreads();              // all threads' fences complete before the atomic
  int* flag = (int*)smem;       // smem free (all LDS reads of epilogue done)
  if (tid == 0) {
    int old = atomicAdd(cnt + cq, 1);
    flag[513] = (old == 63);    // slot 513: clear of red[0..511]
  }
  __syncthreads();
  if (!flag[513]) return;
  __threadfence();              // acquire: see all 64 blocks' P

  // ---- in-kernel reduce for this cq (R13 reduce logic, 512 threads) ----
  float* red = smem;            // [nf 128][cl 4]
  {
    const int cl = tid & 3, nf = tid >> 2;
    float s = 0.f;
#pragma unroll 16
    for (int i = 0; i < 16; ++i)
      s += expf(R[(size_t)(nf + i * 128) * CC + cq * 4 + cl]);
    red[tid] = s;
  }
  __syncthreads();
#pragma unroll
  for (int h = 256; h >= 4; h >>= 1) {
    if (tid < h) red[tid] += red[tid + h];
    __syncthreads();
  }
  const float inv = 1.0f / red[tid >> 7];   // cl = ci = tid>>7 for cell t*4
  __syncthreads();

  {
    const int t4 = tid * 4;
    const float* Pq = P + (size_t)cq * 64 * 2048 + t4;
    float4 s4 = make_float4(0.f, 0.f, 0.f, 0.f);
#pragma unroll 16
    for (int ch = 0; ch < 64; ++ch) {
      float4 v = *(const float4*)(Pq + (size_t)ch * 2048);
      s4.x += v.x; s4.y += v.y; s4.z += v.z; s4.w += v.w;
    }
    s4.x *= inv; s4.y *= inv; s4.z *= inv; s4.w *= inv;

    // cell t4 = (ci*8+bi)*64 + bo*16 + jq*4: ci=t>>7, bi=(t>>4)&7, bo=(t>>2)&3, jq=t&3
    float sq = s4.x * s4.x + s4.y * s4.y + s4.z * s4.z + s4.w * s4.w;
    sq += __shfl_xor(sq, 1, 4);
    sq += __shfl_xor(sq, 2, 4);
    float ss = sq + 1e-7f;
    float scale = sqrtf(ss) / (1.0f + ss);
    s4.x *= scale; s4.y *= scale; s4.z *= scale; s4.w *= scale;

    const int ci = tid >> 7, bi = (tid >> 4) & 7, bo2 = (tid >> 2) & 3, jq = tid & 3;
    const int b = bo2 * 8 + bi, c = cq * 4 + ci;
    *(float4*)(out + (size_t)b * 512 + c * 16 + jq * 4) = s4;
  }
}

extern "C" void kernel_launch(void* const* d_in, const int* in_sizes, int n_in,
                              void* d_out, int out_size, void* d_ws, size_t ws_size,
                              hipStream_t stream) {
  const float* x = (const float*)d_in[0];   // 32*2048*8
  const float* W = (const float*)d_in[1];   // 2048*32*16*8
  const float* R = (const float*)d_in[2];   // 2048*32
  float* out = (float*)d_out;               // 32*32*16

  float* P = (float*)d_ws;                              // 512*2048 floats (4 MB)
  int* cnt = (int*)((char*)d_ws + 4 * 1024 * 1024);     // 8 ints

  hipMemsetAsync(cnt, 0, 32, stream);   // counters must start at 0 every launch

  hipFuncSetAttribute((const void*)caps_fused,
                      hipFuncAttributeMaxDynamicSharedMemorySize, 81920);
  caps_fused<<<512, 512, 81920, stream>>>(x, W, R, P, cnt, out);
}

// Round 16
// 27.451 us; speedup vs baseline: 4.5179x; 4.5179x over previous
//
#include <hip/hip_runtime.h>
#include <math.h>

// Problem: x[B=32][N=2048][K=8], W[N][C=32][J=16][K=8], R[N][C]
// out[b][c][j] = squash_j( sum_n softmax_n(R)[n,c] * sum_k W[n,c,j,k]*x[b,n,k] )
// Main accumulates with UNNORMALIZED w = exp(R[n][c]); reduce computes the
// denominators (cheap per-c block) and normalizes before squash. 2 nodes.
// R16 = R13 byte-for-byte (best measured: 26.7us). R14 (x->VGPR) and R15 (fusion)
// both tripped the hipcc VGPR-allocator wall (clamp to 64 -> serialize/spill).

#define NN 2048
#define CC 32

__device__ __forceinline__ void g2l16(const float* g, float* l) {
  __builtin_amdgcn_global_load_lds((const __attribute__((address_space(1))) void*)g,
                                   (__attribute__((address_space(3))) void*)l, 16, 0, 0);
}

// ---------- Kernel 1: c-quad wave-private contraction, 3-buf ring (2-ahead) ----------
// grid 512: chunk = bid&63 (32 n), cq = bid>>6 (4 c). XCD = bid%8 = chunk%8 -> the 8
// cq-blocks of a chunk share an XCD (x slice L2-resident). block 512 = 8 waves;
// LDS = 8 waves x 2560 f = 80KB -> 2 blocks/CU (16 waves/CU). Wave ws owns
// n = n0+ws*4..+4. Per-wave region: W ring 3x512 f + x 4x256 f.
//   W: per n 128 granules (2 g2l16); slot S holds source granule
//      g = S ^ bit0(S2^S4) ^ bit1(S3) ^ bit2(S4); read slot = (ci*32+j*2+kh)^(j>>1).
//   x: per n 64 granules (1 g2l16; per-lane src does k<->b transpose);
//      slot S = G ^ ((G>>4)<<1), G = b*2+kq.
// Issue order PINNED with sched_barrier(0) so counted-vmcnt arithmetic is exact
// (R9 lesson). Counted vmcnt before EVERY compute (R7/R8/R12/R13 proven);
// lgkmcnt(0) WAR guard before the ring-wrap stage.
// NO occupancy attributes (R4/R6/R15: allocator clamp -> spill or serialization).
__global__ void __launch_bounds__(512) caps_main(const float* __restrict__ x,
                                                 const float* __restrict__ W,
                                                 const float* __restrict__ R,
                                                 float* __restrict__ P) {
  const int bid = blockIdx.x;
  const int cq = bid >> 6;
  const int chunk = bid & 63;
  const int n0 = chunk * 32;
  const int tid = threadIdx.x;
  const int ws = tid >> 6;
  const int lane = tid & 63;
  const int j = lane & 15;
  const int bo = lane >> 4;

  extern __shared__ float smem[];   // 8 x 2560 floats = 80 KB
  float* wREG = smem + ws * 2560;
  float* wW = wREG;                 // ring: 3 bufs x 512
  float* wX = wREG + 1536;          // 4 n x 256
  const int nw = n0 + ws * 4;

  // ---- R loads first (pinned oldest) ----
  float4 rq[4];
#pragma unroll
  for (int nl = 0; nl < 4; ++nl)
    rq[nl] = *(const float4*)(R + (size_t)(nw + nl) * CC + cq * 4);
  __builtin_amdgcn_sched_barrier(0);

  auto stageW = [&](int nl, int buf) {
#pragma unroll
    for (int i = 0; i < 2; ++i) {
      int S = i * 64 + lane;
      int g = S ^ (((S >> 2) ^ (S >> 4)) & 1) ^ (((S >> 3) & 1) << 1) ^ (((S >> 4) & 1) << 2);
      g2l16(W + (size_t)(nw + nl) * 4096 + cq * 512 + g * 4, wW + buf * 512 + i * 256);
    }
  };

  // ---- prologue: W0, x, W1, W2 (pinned order; 10 g2l16 outstanding) ----
  stageW(0, 0);
  __builtin_amdgcn_sched_barrier(0);
  {
    int g2 = lane ^ ((lane >> 4) << 1);   // slot 'lane' holds granule g2
    int b = g2 >> 1, kq = g2 & 1;
    const float* xs = x + (size_t)b * (NN * 8) + kq * 4;
#pragma unroll
    for (int nl = 0; nl < 4; ++nl)
      g2l16(xs + (size_t)(nw + nl) * 8, wX + nl * 256);
  }
  __builtin_amdgcn_sched_barrier(0);
  stageW(1, 1);
  __builtin_amdgcn_sched_barrier(0);
  stageW(2, 2);
  __builtin_amdgcn_sched_barrier(0);

  // unnormalized routing weights (compiler auto-waits for the R loads only)
  float rv[4][4];
#pragma unroll
  for (int nl = 0; nl < 4; ++nl) {
    rv[nl][0] = expf(rq[nl].x);
    rv[nl][1] = expf(rq[nl].y);
    rv[nl][2] = expf(rq[nl].z);
    rv[nl][3] = expf(rq[nl].w);
  }

  float acc[4][8];
#pragma unroll
  for (int a = 0; a < 4; ++a)
#pragma unroll
    for (int b = 0; b < 8; ++b) acc[a][b] = 0.f;

  const int jsw = j >> 1;

  auto compute = [&](int nl, int buf) {
    const float* Wn = wW + buf * 512;
    const float* Xn = wX + nl * 256;
#pragma unroll
    for (int kh = 0; kh < 2; ++kh) {
      float4 xv[8];
#pragma unroll
      for (int bi = 0; bi < 8; ++bi) {
        int G = (bo * 8 + bi) * 2 + kh;
        int S = G ^ ((G >> 4) << 1);
        xv[bi] = *(const float4*)(Xn + S * 4);
      }
#pragma unroll
      for (int ci = 0; ci < 4; ++ci) {
        int slot = (ci * 32 + j * 2 + kh) ^ jsw;
        float4 wf = *(const float4*)(Wn + slot * 4);
        float rvv = rv[nl][ci];
        float w0 = wf.x * rvv, w1 = wf.y * rvv, w2 = wf.z * rvv, w3 = wf.w * rvv;
#pragma unroll
        for (int bi = 0; bi < 8; ++bi) {
          float a = acc[ci][bi];
          a = fmaf(w0, xv[bi].x, a);
          a = fmaf(w1, xv[bi].y, a);
          a = fmaf(w2, xv[bi].z, a);
          a = fmaf(w3, xv[bi].w, a);
          acc[ci][bi] = a;
        }
      }
    }
  };

  // ---- pipeline: 2-ahead ring; counted waits only; 0 barriers ----
  asm volatile("s_waitcnt vmcnt(4)" ::: "memory");   // W0 + x landed (W1,W2 in flight)
  __builtin_amdgcn_sched_barrier(0);
  compute(0, 0);
  asm volatile("s_waitcnt lgkmcnt(0)" ::: "memory"); // compute0 LDS reads retired
  __builtin_amdgcn_sched_barrier(0);
  stageW(3, 0);                                      // ring wrap onto buf0
  __builtin_amdgcn_sched_barrier(0);
  asm volatile("s_waitcnt vmcnt(4)" ::: "memory");   // W1 landed (W2,W3 in flight)
  __builtin_amdgcn_sched_barrier(0);
  compute(1, 1);
  asm volatile("s_waitcnt vmcnt(2)" ::: "memory");   // W2 landed (W3 in flight)
  __builtin_amdgcn_sched_barrier(0);
  compute(2, 2);
  asm volatile("s_waitcnt vmcnt(0)" ::: "memory");   // W3 landed
  __builtin_amdgcn_sched_barrier(0);
  compute(3, 0);

  // ---- epilogue: dump into own region (in-wave DS order safe), 1 barrier ----
#pragma unroll
  for (int ci = 0; ci < 4; ++ci)
#pragma unroll
    for (int bi = 0; bi < 8; ++bi)
      wREG[(ci * 8 + bi) * 64 + lane] = acc[ci][bi];
  __syncthreads();
  {
    const int t4 = tid * 4;
    float4 ssum = make_float4(0.f, 0.f, 0.f, 0.f);
#pragma unroll
    for (int w = 0; w < 8; ++w) {
      float4 v = *(const float4*)(smem + (size_t)w * 2560 + t4);
      ssum.x += v.x; ssum.y += v.y; ssum.z += v.z; ssum.w += v.w;
    }
    *(float4*)(P + (size_t)bid * 2048 + t4) = ssum;
  }
}

// ---------- Kernel 2: per-c denominator + float4 cross-chunk reduce + squash ----------
// 32 blocks (one per c) x 128 threads. t = b*4 + jq (b 0..31, jq 0..3).
// Denominator: 16 exp/thread + wave shfl reduce (1 barrier).
// P[bid = cq*64 + ch][cell = (ci*8+bi)*64 + bo*16 + j]; f4 over j-quad.
__global__ void caps_reduce(const float* __restrict__ P, const float* __restrict__ R,
                            float* __restrict__ out) {
  const int c = blockIdx.x;
  const int t = threadIdx.x;
  const int b = t >> 2, jq = t & 3;

  __shared__ float red[2];
  {
    float s = 0.f;
#pragma unroll
    for (int i = 0; i < 16; ++i)
      s += expf(R[(size_t)(t + i * 128) * CC + c]);
#pragma unroll
    for (int d = 32; d >= 1; d >>= 1) s += __shfl_xor(s, d, 64);
    if ((t & 63) == 0) red[t >> 6] = s;
  }
  __syncthreads();
  const float inv = 1.0f / (red[0] + red[1]);

  const int cq = c >> 2, ci = c & 3;
  const int bo = b >> 3, bi = b & 7;
  const int cell = (ci * 8 + bi) * 64 + bo * 16 + jq * 4;
  const float* Pq = P + (size_t)cq * 64 * 2048 + cell;

  float4 s4 = make_float4(0.f, 0.f, 0.f, 0.f);
#pragma unroll 16
  for (int ch = 0; ch < 64; ++ch) {
    float4 v = *(const float4*)(Pq + (size_t)ch * 2048);
    s4.x += v.x; s4.y += v.y; s4.z += v.z; s4.w += v.w;
  }
  s4.x *= inv; s4.y *= inv; s4.z *= inv; s4.w *= inv;

  float sq = s4.x * s4.x + s4.y * s4.y + s4.z * s4.z + s4.w * s4.w;
  sq += __shfl_xor(sq, 1, 4);
  sq += __shfl_xor(sq, 2, 4);
  float ss = sq + 1e-7f;
  float scale = sqrtf(ss) / (1.0f + ss);
  s4.x *= scale; s4.y *= scale; s4.z *= scale; s4.w *= scale;

  *(float4*)(out + (size_t)b * 512 + c * 16 + jq * 4) = s4;
}

extern "C" void kernel_launch(void* const* d_in, const int* in_sizes, int n_in,
                              void* d_out, int out_size, void* d_ws, size_t ws_size,
                              hipStream_t stream) {
  const float* x = (const float*)d_in[0];   // 32*2048*8
  const float* W = (const float*)d_in[1];   // 2048*32*16*8
  const float* R = (const float*)d_in[2];   // 2048*32
  float* out = (float*)d_out;               // 32*32*16
  float* P = (float*)d_ws;                  // 512*2048 floats (4 MB)

  hipFuncSetAttribute((const void*)caps_main,
                      hipFuncAttributeMaxDynamicSharedMemorySize, 81920);

  caps_main<<<512, 512, 81920, stream>>>(x, W, R, P);
  caps_reduce<<<32, 128, 0, stream>>>(P, R, out);
}